// Round 3
// baseline (3399.126 us; speedup 1.0000x reference)
//
#include <hip/hip_runtime.h>
#include <hip/hip_bf16.h>
#include <math.h>

constexpr int NB = 256;    // batch
constexpr int NS = 512;    // source positions
constexpr int ND = 1024;   // hidden
constexpr int NV = 50257;  // vocab
constexpr int NTILES_V = (NV + 63) / 64;   // 786

typedef __attribute__((ext_vector_type(8))) short bf16x8;
typedef __attribute__((ext_vector_type(4))) float f32x4;

__device__ __forceinline__ short f2bf(float f) {
  unsigned u = __builtin_bit_cast(unsigned, f);
  u = (u + 0x7FFFu + ((u >> 16) & 1u)) >> 16;   // RNE
  return (short)u;
}

// swizzle: chunk position = slot ^ SWZ(row). Self-inverse, consistent on write+read.
__device__ __forceinline__ int swz(int r) { return (r & 7) ^ ((r >> 3) & 1); }

__device__ __forceinline__ const bf16x8* fragAddr(const short* base, int r, int slot) {
  return reinterpret_cast<const bf16x8*>(
      reinterpret_cast<const char*>(base) + r * 128 + ((slot ^ swz(r)) << 4));
}

__device__ __forceinline__ void async_copy16(const void* gsrc, void* ldsdst) {
  __builtin_amdgcn_global_load_lds(
      (const __attribute__((address_space(1))) unsigned int*)gsrc,
      (__attribute__((address_space(3))) unsigned int*)ldsdst, 16, 0, 0);
}

// ---------------------------------------------------------------------------
// prep_x: xb[m][kt][chunkpos] bf16, pre-swizzled so GEMM A-staging is a linear
// global_load_lds copy. One chunk (8 k) per thread.
// ---------------------------------------------------------------------------
__global__ __launch_bounds__(256)
void prep_x(const float* __restrict__ x, short* __restrict__ xb) {
  int idx = blockIdx.x * 256 + threadIdx.x;      // 32768 chunks
  int m = idx >> 7, kt = (idx >> 3) & 15, slot = idx & 7;
  const float4* src = reinterpret_cast<const float4*>(x + m * ND + kt * 64 + slot * 8);
  float4 f0 = src[0], f1 = src[1];
  bf16x8 v = { f2bf(f0.x), f2bf(f0.y), f2bf(f0.z), f2bf(f0.w),
               f2bf(f1.x), f2bf(f1.y), f2bf(f1.z), f2bf(f1.w) };
  *reinterpret_cast<bf16x8*>(reinterpret_cast<char*>(xb) +
      m * 2048 + kt * 128 + ((slot ^ swz(m)) << 4)) = v;
}

// ---------------------------------------------------------------------------
// Pipelined MFMA GEMM: C[256,N] = act(x @ W + bias), W f32 [1024][N] k-major.
// BM=128 BN=64 BK=64, 4 waves, 3-deep pipeline:
//   regs(B, t+2) | gload_lds(A, t+1) + transpose-write(B, t+1) | compute(t)
// GATE: tanh into h. !GATE: raw logits + fused per-row partial max/sum.
// ---------------------------------------------------------------------------
__device__ __forceinline__ void loadB(const float* __restrict__ W, int ldN, bool okc,
                                      int n0, int w, int lane, int t, float v[16]) {
#pragma unroll
  for (int i = 0; i < 16; ++i) {
    v[i] = 0.f;
    if (okc) v[i] = W[(size_t)(t * 64 + w * 16 + i) * ldN + n0 + lane];
  }
}

__device__ __forceinline__ void gloadA(const short* __restrict__ xb, int rowbase,
                                       int w, int lane, int t, short* AsN) {
#pragma unroll
  for (int j = 0; j < 4; ++j) {
    int chunk = (w * 4 + j) * 64 + lane;         // 0..1023
    int ml = chunk >> 3, p = chunk & 7;
    const char* src = reinterpret_cast<const char*>(xb) +
        ((size_t)(rowbase + ml) << 11) + (t << 7) + (p << 4);
    async_copy16(src, reinterpret_cast<char*>(AsN) + ((w * 4 + j) << 10));
  }
}

__device__ __forceinline__ void transB(const float v[16], short* BsN, int w, int lane) {
  bf16x8 lo = { f2bf(v[0]), f2bf(v[1]), f2bf(v[2]), f2bf(v[3]),
                f2bf(v[4]), f2bf(v[5]), f2bf(v[6]), f2bf(v[7]) };
  bf16x8 hi = { f2bf(v[8]), f2bf(v[9]), f2bf(v[10]), f2bf(v[11]),
                f2bf(v[12]), f2bf(v[13]), f2bf(v[14]), f2bf(v[15]) };
  char* row = reinterpret_cast<char*>(BsN) + lane * 128;
  *reinterpret_cast<bf16x8*>(row + (((w * 2 + 0) ^ swz(lane)) << 4)) = lo;
  *reinterpret_cast<bf16x8*>(row + (((w * 2 + 1) ^ swz(lane)) << 4)) = hi;
}

__device__ __forceinline__ void computeStep(const short* A, const short* B,
                                            int w, int g, int c16, f32x4 acc[2][4]) {
#pragma unroll
  for (int kk = 0; kk < 2; ++kk) {
    int slot = kk * 4 + g;
    bf16x8 a0 = *fragAddr(A, w * 32 + c16, slot);
    bf16x8 a1 = *fragAddr(A, w * 32 + 16 + c16, slot);
    bf16x8 b[4];
#pragma unroll
    for (int ni = 0; ni < 4; ++ni) b[ni] = *fragAddr(B, ni * 16 + c16, slot);
#pragma unroll
    for (int ni = 0; ni < 4; ++ni) {
      acc[0][ni] = __builtin_amdgcn_mfma_f32_16x16x32_bf16(a0, b[ni], acc[0][ni], 0, 0, 0);
      acc[1][ni] = __builtin_amdgcn_mfma_f32_16x16x32_bf16(a1, b[ni], acc[1][ni], 0, 0, 0);
    }
  }
}

template<bool GATE>
__global__ __launch_bounds__(256, 3)
void gemm_mfma(const short* __restrict__ xb, const float* __restrict__ W,
               const float* __restrict__ bias, float* __restrict__ Cout,
               float* __restrict__ partials, int N, int ntiles) {
  __shared__ __align__(16) short As[2][128 * 64];   // 16KB x2
  __shared__ __align__(16) short Bs[2][64 * 64];    // 8KB x2
  const int tid = threadIdx.x;
  const int lane = tid & 63, w = tid >> 6;
  const int g = lane >> 4, c16 = lane & 15;
  const int n0 = blockIdx.x * 64;
  const int rowbase = blockIdx.y * 128;
  const bool okc = (n0 + lane) < N;

  float vb0[16], vb1[16];
  f32x4 acc[2][4] = {};

  // prologue
  loadB(W, N, okc, n0, w, lane, 0, vb0);
  gloadA(xb, rowbase, w, lane, 0, As[0]);
  transB(vb0, Bs[0], w, lane);             // compiler waits on vb0 arrival
  loadB(W, N, okc, n0, w, lane, 1, vb1);
  __syncthreads();                         // drains vmem (A DMA), Bs0 visible

#define GBODY(T, CUR, VLOAD, VTRANS)                                    \
  {                                                                     \
    if ((T) + 2 < 16) loadB(W, N, okc, n0, w, lane, (T) + 2, VLOAD);    \
    if ((T) + 1 < 16) gloadA(xb, rowbase, w, lane, (T) + 1, As[1 - (CUR)]); \
    if ((T) + 1 < 16) transB(VTRANS, Bs[1 - (CUR)], w, lane);           \
    computeStep(As[CUR], Bs[CUR], w, g, c16, acc);                      \
    __syncthreads();                                                    \
  }

  for (int t = 0; t < 16; t += 2) {
    GBODY(t, 0, vb0, vb1);
    GBODY(t + 1, 1, vb1, vb0);
  }
#undef GBODY

  // epilogue: C/D layout col = lane&15, row = (lane>>4)*4 + reg
#pragma unroll
  for (int mi = 0; mi < 2; ++mi) {
#pragma unroll
    for (int r = 0; r < 4; ++r) {
      int row = rowbase + w * 32 + mi * 16 + g * 4 + r;
      float vals[4];
      float pm = -3.0e38f;
#pragma unroll
      for (int ni = 0; ni < 4; ++ni) {
        int col = n0 + ni * 16 + c16;
        bool ok2 = col < N;
        float bv = ok2 ? bias[col] : 0.f;
        float v = acc[mi][ni][r] + bv;
        if (GATE) v = tanhf(v);
        vals[ni] = v;
        if (ok2) {
          Cout[(size_t)row * N + col] = v;
          pm = fmaxf(pm, v);
        }
      }
      if (!GATE) {
        float ps = 0.f;
#pragma unroll
        for (int ni = 0; ni < 4; ++ni) {
          int col = n0 + ni * 16 + c16;
          if (col < N) ps += expf(vals[ni] - pm);
        }
#pragma unroll
        for (int o = 1; o < 16; o <<= 1) {
          float m2 = __shfl_xor(pm, o, 64);
          float s2 = __shfl_xor(ps, o, 64);
          float mn = fmaxf(pm, m2);
          ps = ps * expf(pm - mn) + s2 * expf(m2 - mn);
          pm = mn;
        }
        if (c16 == 0) {
          partials[((size_t)row * ntiles + blockIdx.x) * 2 + 0] = pm;
          partials[((size_t)row * ntiles + blockIdx.x) * 2 + 1] = ps;
        }
      }
    }
  }
}

// ---------------------------------------------------------------------------
// combine per-row partial (max,sum) over ntiles -> stats
// ---------------------------------------------------------------------------
__global__ __launch_bounds__(256)
void combine_stats(const float* __restrict__ partials, float* __restrict__ stats,
                   int ntiles) {
  int row = blockIdx.x, tid = threadIdx.x;
  float m = -3.0e38f, s = 0.f;
  for (int j = tid; j < ntiles; j += 256) {
    float pm = partials[((size_t)row * ntiles + j) * 2 + 0];
    float ps = partials[((size_t)row * ntiles + j) * 2 + 1];
    float mn = fmaxf(m, pm);
    s = s * expf(m - mn) + ps * expf(pm - mn);
    m = mn;
  }
#pragma unroll
  for (int o = 1; o < 64; o <<= 1) {
    float m2 = __shfl_xor(m, o, 64);
    float s2 = __shfl_xor(s, o, 64);
    float mn = fmaxf(m, m2);
    s = s * expf(m - mn) + s2 * expf(m2 - mn);
    m = mn;
  }
  __shared__ float lm[4], ls[4];
  int wv = tid >> 6, ln = tid & 63;
  if (ln == 0) { lm[wv] = m; ls[wv] = s; }
  __syncthreads();
  if (tid == 0) {
    float M = lm[0], S = ls[0];
    for (int k = 1; k < 4; ++k) {
      float mn = fmaxf(M, lm[k]);
      S = S * expf(M - mn) + ls[k] * expf(lm[k] - mn);
      M = mn;
    }
    stats[row * 2 + 0] = M;
    stats[row * 2 + 1] = S;
  }
}

// ---------------------------------------------------------------------------
// mix = softmax2(h @ W2 + b2), one block per row
// ---------------------------------------------------------------------------
__global__ __launch_bounds__(256)
void gate_mix(const float* __restrict__ h, const float* __restrict__ W2,
              const float* __restrict__ b2, float* __restrict__ mix) {
  const int row = blockIdx.x;
  const int tid = threadIdx.x;
  float g0 = 0.f, g1 = 0.f;
  for (int j = tid; j < ND; j += 256) {
    float hv = h[row * ND + j];
    g0 += hv * W2[j * 2 + 0];
    g1 += hv * W2[j * 2 + 1];
  }
  for (int o = 32; o > 0; o >>= 1) {
    g0 += __shfl_down(g0, o, 64);
    g1 += __shfl_down(g1, o, 64);
  }
  __shared__ float l0[4], l1[4];
  int wid = tid >> 6, lane = tid & 63;
  if (lane == 0) { l0[wid] = g0; l1[wid] = g1; }
  __syncthreads();
  if (tid == 0) {
    float a = l0[0] + l0[1] + l0[2] + l0[3] + b2[0];
    float c = l1[0] + l1[1] + l1[2] + l1[3] + b2[1];
    float m = fmaxf(a, c);
    float e0 = expf(a - m), e1 = expf(c - m);
    float inv = 1.f / (e0 + e1);
    mix[row * 2 + 0] = e0 * inv;
    mix[row * 2 + 1] = e1 * inv;
  }
}

// ---------------------------------------------------------------------------
// alphas = softmax(scores) rowwise
// ---------------------------------------------------------------------------
__global__ __launch_bounds__(256)
void softmax_scores(const float* __restrict__ scores, float* __restrict__ alphas) {
  const int row = blockIdx.x;
  const int tid = threadIdx.x;
  float v0 = scores[row * NS + tid];
  float v1 = scores[row * NS + tid + 256];
  float m = fmaxf(v0, v1);
  for (int o = 32; o > 0; o >>= 1) m = fmaxf(m, __shfl_down(m, o, 64));
  __shared__ float lm[4], ls[4];
  int wid = tid >> 6, lane = tid & 63;
  if (lane == 0) lm[wid] = m;
  __syncthreads();
  float mAll = fmaxf(fmaxf(lm[0], lm[1]), fmaxf(lm[2], lm[3]));
  float e0 = expf(v0 - mAll), e1 = expf(v1 - mAll);
  float s = e0 + e1;
  for (int o = 32; o > 0; o >>= 1) s += __shfl_down(s, o, 64);
  if (lane == 0) ls[wid] = s;
  __syncthreads();
  float inv = 1.f / (ls[0] + ls[1] + ls[2] + ls[3]);
  alphas[row * NS + tid] = e0 * inv;
  alphas[row * NS + tid + 256] = e1 * inv;
}

// ---------------------------------------------------------------------------
// out = exp(logit - m)/s * mix0   (in-place on d_out)
// ---------------------------------------------------------------------------
__global__ __launch_bounds__(256)
void finalize_gen(float* __restrict__ out, const float* __restrict__ stats,
                  const float* __restrict__ mix) {
  const int row = blockIdx.y;
  const int col = blockIdx.x * 256 + threadIdx.x;
  if (col < NV) {
    float m = stats[row * 2 + 0], s = stats[row * 2 + 1];
    float gmul = mix[row * 2 + 0];
    float x = out[(size_t)row * NV + col];
    out[(size_t)row * NV + col] = expf(x - m) * (gmul / s);
  }
}

// ---------------------------------------------------------------------------
// out[row, ctx_ids[row,s]] += alphas[row,s] * mix1[row]
// ---------------------------------------------------------------------------
__global__ __launch_bounds__(512)
void scatter_copy(float* __restrict__ out, const float* __restrict__ alphas,
                  const int* __restrict__ ids, const float* __restrict__ mix) {
  const int row = blockIdx.x;
  const int t = threadIdx.x;
  float a = alphas[row * NS + t] * mix[row * 2 + 1];
  atomicAdd(&out[(size_t)row * NV + ids[row * NS + t]], a);
}

extern "C" void kernel_launch(void* const* d_in, const int* in_sizes, int n_in,
                              void* d_out, int out_size, void* d_ws, size_t ws_size,
                              hipStream_t stream) {
  const float* x      = (const float*)d_in[0];
  const float* scores = (const float*)d_in[1];
  const int*   ctx    = (const int*)d_in[2];
  const float* Wg     = (const float*)d_in[3];
  const float* bg     = (const float*)d_in[4];
  const float* W1     = (const float*)d_in[5];
  const float* b1     = (const float*)d_in[6];
  const float* W2     = (const float*)d_in[7];
  const float* b2     = (const float*)d_in[8];
  float* out = (float*)d_out;

  short* xb       = (short*)d_ws;                                   // 512 KB
  float* partials = (float*)((char*)d_ws + 512 * 1024);             // 256*786*2 f32
  float* mix      = partials + (size_t)NB * NTILES_V * 2;
  float* stats    = mix + NB * 2;
  float* alphas   = stats + NB * 2;
  float* h        = alphas + NB * NS;

  // x -> bf16, pre-swizzled for linear global_load_lds staging
  prep_x<<<128, 256, 0, stream>>>(x, xb);
  // h = tanh(x @ W1 + b1)
  gemm_mfma<true><<<dim3(16, 2), 256, 0, stream>>>(xb, W1, b1, h, nullptr, ND, 16);
  // mix = softmax2(h @ W2 + b2)
  gate_mix<<<NB, 256, 0, stream>>>(h, W2, b2, mix);
  // alphas = softmax(scores)
  softmax_scores<<<NB, 256, 0, stream>>>(scores, alphas);
  // logits = x @ Wg + bg -> d_out, with fused per-row partial max/sum
  gemm_mfma<false><<<dim3(NTILES_V, 2), 256, 0, stream>>>(xb, Wg, bg, out, partials, NV, NTILES_V);
  // combine partials -> stats
  combine_stats<<<NB, 256, 0, stream>>>(partials, stats, NTILES_V);
  // out = softmax * mix0 (in place)
  finalize_gen<<<dim3((NV + 255) / 256, NB), 256, 0, stream>>>(out, stats, mix);
  // scatter copy distribution
  scatter_copy<<<NB, NS, 0, stream>>>(out, alphas, ctx, mix);
}

// Round 4
// 205.610 us; speedup vs baseline: 16.5319x; 16.5319x over previous
//
#include <hip/hip_runtime.h>
#include <hip/hip_bf16.h>
#include <math.h>

constexpr int NB = 256;    // batch
constexpr int NS = 512;    // source positions
constexpr int ND = 1024;   // hidden
constexpr int NV = 50257;  // vocab
constexpr int NTILES_V = (NV + 63) / 64;   // 786

typedef __attribute__((ext_vector_type(8))) short bf16x8;
typedef __attribute__((ext_vector_type(4))) float f32x4;

__device__ __forceinline__ short f2bf(float f) {
  unsigned u = __builtin_bit_cast(unsigned, f);
  u = (u + 0x7FFFu + ((u >> 16) & 1u)) >> 16;   // RNE
  return (short)u;
}

// swizzle: chunk position = slot ^ swz(row). Self-inverse; used on write+read.
__device__ __forceinline__ int swz(int r) { return (r & 7) ^ ((r >> 3) & 1); }

__device__ __forceinline__ const bf16x8* fragAddr(const short* base, int r, int slot) {
  return reinterpret_cast<const bf16x8*>(
      reinterpret_cast<const char*>(base) + r * 128 + ((slot ^ swz(r)) << 4));
}

__device__ __forceinline__ void async_copy16(const void* gsrc, void* ldsdst) {
  __builtin_amdgcn_global_load_lds(
      (const __attribute__((address_space(1))) unsigned int*)gsrc,
      (__attribute__((address_space(3))) unsigned int*)ldsdst, 16, 0, 0);
}

// ---------------------------------------------------------------------------
// prep_x: xb[m][kt][chunkpos] bf16, pre-swizzled so GEMM A-staging is a linear
// global_load_lds copy. One 16B chunk (8 k) per thread.
// ---------------------------------------------------------------------------
__global__ __launch_bounds__(256)
void prep_x(const float* __restrict__ x, short* __restrict__ xb) {
  int idx = blockIdx.x * 256 + threadIdx.x;      // 32768 chunks
  int m = idx >> 7, kt = (idx >> 3) & 15, slot = idx & 7;
  const float4* src = reinterpret_cast<const float4*>(x + m * ND + kt * 64 + slot * 8);
  float4 f0 = src[0], f1 = src[1];
  bf16x8 v = { f2bf(f0.x), f2bf(f0.y), f2bf(f0.z), f2bf(f0.w),
               f2bf(f1.x), f2bf(f1.y), f2bf(f1.z), f2bf(f1.w) };
  *reinterpret_cast<bf16x8*>(reinterpret_cast<char*>(xb) +
      m * 2048 + kt * 128 + ((slot ^ swz(m)) << 4)) = v;
}

// ---------------------------------------------------------------------------
// MFMA GEMM: C[256,N] = act(x @ W + bias). BM=256 (full M, W streamed once),
// BN=64, BK=64, 4 waves, single-buffered LDS, 2 barriers/K-step.
// A: global_load_lds from pre-swizzled xb. B: 16 coalesced dword loads ->
// f2bf -> 2x ds_write_b128 transpose (next step's B issued before barrier 2).
// ---------------------------------------------------------------------------
__device__ __forceinline__ void loadB(const float* __restrict__ W, int ldN, bool okc,
                                      int n0, int w, int lane, int t, float v[16]) {
#pragma unroll
  for (int i = 0; i < 16; ++i)
    v[i] = okc ? W[(size_t)(t * 64 + w * 16 + i) * ldN + n0 + lane] : 0.f;
}

__device__ __forceinline__ void gloadA(const short* __restrict__ xb,
                                       int w, int lane, int t, short* AsN) {
#pragma unroll
  for (int j = 0; j < 8; ++j) {
    int chunk = (w * 8 + j) * 64 + lane;         // 0..2047
    int ml = chunk >> 3, p = chunk & 7;
    const char* src = reinterpret_cast<const char*>(xb) +
        (ml << 11) + (t << 7) + (p << 4);
    async_copy16(src, reinterpret_cast<char*>(AsN) + ((w * 8 + j) << 10));
  }
}

__device__ __forceinline__ void transB(const float v[16], short* BsN, int w, int lane) {
  bf16x8 lo = { f2bf(v[0]), f2bf(v[1]), f2bf(v[2]), f2bf(v[3]),
                f2bf(v[4]), f2bf(v[5]), f2bf(v[6]), f2bf(v[7]) };
  bf16x8 hi = { f2bf(v[8]), f2bf(v[9]), f2bf(v[10]), f2bf(v[11]),
                f2bf(v[12]), f2bf(v[13]), f2bf(v[14]), f2bf(v[15]) };
  char* row = reinterpret_cast<char*>(BsN) + lane * 128;
  *reinterpret_cast<bf16x8*>(row + (((w * 2 + 0) ^ swz(lane)) << 4)) = lo;
  *reinterpret_cast<bf16x8*>(row + (((w * 2 + 1) ^ swz(lane)) << 4)) = hi;
}

__device__ __forceinline__ void computeStep(const short* A, const short* B,
                                            int w, int g, int c16, f32x4 acc[4][4]) {
#pragma unroll
  for (int kk = 0; kk < 2; ++kk) {
    int slot = kk * 4 + g;
    bf16x8 b[4];
#pragma unroll
    for (int ni = 0; ni < 4; ++ni) b[ni] = *fragAddr(B, ni * 16 + c16, slot);
#pragma unroll
    for (int mi = 0; mi < 4; ++mi) {
      bf16x8 a = *fragAddr(A, w * 64 + mi * 16 + c16, slot);
#pragma unroll
      for (int ni = 0; ni < 4; ++ni)
        acc[mi][ni] = __builtin_amdgcn_mfma_f32_16x16x32_bf16(a, b[ni], acc[mi][ni], 0, 0, 0);
    }
  }
}

template<bool GATE>
__global__ __launch_bounds__(256, 3)
void gemm_mfma(const short* __restrict__ xb, const float* __restrict__ W,
               const float* __restrict__ bias, float* __restrict__ Cout,
               float* __restrict__ partials, int N, int ntiles) {
  __shared__ __align__(16) short As[256 * 64];   // 32 KB
  __shared__ __align__(16) short Bs[64 * 64];    // 8 KB
  const int tid = threadIdx.x;
  const int lane = tid & 63, w = tid >> 6;
  const int g = lane >> 4, c16 = lane & 15;
  const int n0 = blockIdx.x * 64;
  const bool okc = (n0 + lane) < N;

  f32x4 acc[4][4] = {};
  float vbA[16], vbN[16];

  loadB(W, N, okc, n0, w, lane, 0, vbA);

#pragma unroll 1
  for (int t = 0; t < 16; ++t) {
    __syncthreads();                        // LDS free (compute t-1 done)
    gloadA(xb, w, lane, t, As);             // 8 DMA issues -> As
    int tn = (t < 15) ? t + 1 : 15;         // last iter: redundant in-bounds load
    loadB(W, N, okc, n0, w, lane, tn, vbN); // next B in flight over transB/DMA
    transB(vbA, Bs, w, lane);               // waits vbA arrival; LDS writes
    __syncthreads();                        // drains DMA + loads + LDS writes
    computeStep(As, Bs, w, g, c16, acc);
#pragma unroll
    for (int i = 0; i < 16; ++i) vbA[i] = vbN[i];
  }

  // epilogue: C/D layout col = lane&15, row = (lane>>4)*4 + reg
#pragma unroll
  for (int mi = 0; mi < 4; ++mi) {
#pragma unroll
    for (int r = 0; r < 4; ++r) {
      int row = w * 64 + mi * 16 + g * 4 + r;
      float vals[4];
      float pm = -3.0e38f;
#pragma unroll
      for (int ni = 0; ni < 4; ++ni) {
        int col = n0 + ni * 16 + c16;
        bool ok2 = col < N;
        float bv = ok2 ? bias[col] : 0.f;
        float v = acc[mi][ni][r] + bv;
        if (GATE) v = tanhf(v);
        vals[ni] = v;
        if (ok2) {
          Cout[(size_t)row * N + col] = v;
          pm = fmaxf(pm, v);
        }
      }
      if (!GATE) {
        float ps = 0.f;
#pragma unroll
        for (int ni = 0; ni < 4; ++ni) {
          int col = n0 + ni * 16 + c16;
          if (col < N) ps += expf(vals[ni] - pm);
        }
#pragma unroll
        for (int o = 1; o < 16; o <<= 1) {
          float m2 = __shfl_xor(pm, o, 64);
          float s2 = __shfl_xor(ps, o, 64);
          float mn = fmaxf(pm, m2);
          ps = ps * expf(pm - mn) + s2 * expf(m2 - mn);
          pm = mn;
        }
        if (c16 == 0) {
          partials[((size_t)row * ntiles + blockIdx.x) * 2 + 0] = pm;
          partials[((size_t)row * ntiles + blockIdx.x) * 2 + 1] = ps;
        }
      }
    }
  }
}

// ---------------------------------------------------------------------------
// combine per-row partial (max,sum) over ntiles -> stats
// ---------------------------------------------------------------------------
__global__ __launch_bounds__(256)
void combine_stats(const float* __restrict__ partials, float* __restrict__ stats,
                   int ntiles) {
  int row = blockIdx.x, tid = threadIdx.x;
  float m = -3.0e38f, s = 0.f;
  for (int j = tid; j < ntiles; j += 256) {
    float pm = partials[((size_t)row * ntiles + j) * 2 + 0];
    float ps = partials[((size_t)row * ntiles + j) * 2 + 1];
    float mn = fmaxf(m, pm);
    s = s * expf(m - mn) + ps * expf(pm - mn);
    m = mn;
  }
#pragma unroll
  for (int o = 1; o < 64; o <<= 1) {
    float m2 = __shfl_xor(m, o, 64);
    float s2 = __shfl_xor(s, o, 64);
    float mn = fmaxf(m, m2);
    s = s * expf(m - mn) + s2 * expf(m2 - mn);
    m = mn;
  }
  __shared__ float lm[4], ls[4];
  int wv = tid >> 6, ln = tid & 63;
  if (ln == 0) { lm[wv] = m; ls[wv] = s; }
  __syncthreads();
  if (tid == 0) {
    float M = lm[0], S = ls[0];
    for (int k = 1; k < 4; ++k) {
      float mn = fmaxf(M, lm[k]);
      S = S * expf(M - mn) + ls[k] * expf(lm[k] - mn);
      M = mn;
    }
    stats[row * 2 + 0] = M;
    stats[row * 2 + 1] = S;
  }
}

// ---------------------------------------------------------------------------
// mix = softmax2(h @ W2 + b2), one block per row
// ---------------------------------------------------------------------------
__global__ __launch_bounds__(256)
void gate_mix(const float* __restrict__ h, const float* __restrict__ W2,
              const float* __restrict__ b2, float* __restrict__ mix) {
  const int row = blockIdx.x;
  const int tid = threadIdx.x;
  float g0 = 0.f, g1 = 0.f;
  for (int j = tid; j < ND; j += 256) {
    float hv = h[row * ND + j];
    g0 += hv * W2[j * 2 + 0];
    g1 += hv * W2[j * 2 + 1];
  }
  for (int o = 32; o > 0; o >>= 1) {
    g0 += __shfl_down(g0, o, 64);
    g1 += __shfl_down(g1, o, 64);
  }
  __shared__ float l0[4], l1[4];
  int wid = tid >> 6, lane = tid & 63;
  if (lane == 0) { l0[wid] = g0; l1[wid] = g1; }
  __syncthreads();
  if (tid == 0) {
    float a = l0[0] + l0[1] + l0[2] + l0[3] + b2[0];
    float c = l1[0] + l1[1] + l1[2] + l1[3] + b2[1];
    float m = fmaxf(a, c);
    float e0 = expf(a - m), e1 = expf(c - m);
    float inv = 1.f / (e0 + e1);
    mix[row * 2 + 0] = e0 * inv;
    mix[row * 2 + 1] = e1 * inv;
  }
}

// ---------------------------------------------------------------------------
// alphas = softmax(scores) rowwise
// ---------------------------------------------------------------------------
__global__ __launch_bounds__(256)
void softmax_scores(const float* __restrict__ scores, float* __restrict__ alphas) {
  const int row = blockIdx.x;
  const int tid = threadIdx.x;
  float v0 = scores[row * NS + tid];
  float v1 = scores[row * NS + tid + 256];
  float m = fmaxf(v0, v1);
  for (int o = 32; o > 0; o >>= 1) m = fmaxf(m, __shfl_down(m, o, 64));
  __shared__ float lm[4], ls[4];
  int wid = tid >> 6, lane = tid & 63;
  if (lane == 0) lm[wid] = m;
  __syncthreads();
  float mAll = fmaxf(fmaxf(lm[0], lm[1]), fmaxf(lm[2], lm[3]));
  float e0 = expf(v0 - mAll), e1 = expf(v1 - mAll);
  float s = e0 + e1;
  for (int o = 32; o > 0; o >>= 1) s += __shfl_down(s, o, 64);
  if (lane == 0) ls[wid] = s;
  __syncthreads();
  float inv = 1.f / (ls[0] + ls[1] + ls[2] + ls[3]);
  alphas[row * NS + tid] = e0 * inv;
  alphas[row * NS + tid + 256] = e1 * inv;
}

// ---------------------------------------------------------------------------
// out = exp(logit - m)/s * mix0   (in-place on d_out)
// ---------------------------------------------------------------------------
__global__ __launch_bounds__(256)
void finalize_gen(float* __restrict__ out, const float* __restrict__ stats,
                  const float* __restrict__ mix) {
  const int row = blockIdx.y;
  const int col = blockIdx.x * 256 + threadIdx.x;
  if (col < NV) {
    float m = stats[row * 2 + 0], s = stats[row * 2 + 1];
    float gmul = mix[row * 2 + 0];
    float x = out[(size_t)row * NV + col];
    out[(size_t)row * NV + col] = expf(x - m) * (gmul / s);
  }
}

// ---------------------------------------------------------------------------
// out[row, ctx_ids[row,s]] += alphas[row,s] * mix1[row]
// ---------------------------------------------------------------------------
__global__ __launch_bounds__(512)
void scatter_copy(float* __restrict__ out, const float* __restrict__ alphas,
                  const int* __restrict__ ids, const float* __restrict__ mix) {
  const int row = blockIdx.x;
  const int t = threadIdx.x;
  float a = alphas[row * NS + t] * mix[row * 2 + 1];
  atomicAdd(&out[(size_t)row * NV + ids[row * NS + t]], a);
}

extern "C" void kernel_launch(void* const* d_in, const int* in_sizes, int n_in,
                              void* d_out, int out_size, void* d_ws, size_t ws_size,
                              hipStream_t stream) {
  const float* x      = (const float*)d_in[0];
  const float* scores = (const float*)d_in[1];
  const int*   ctx    = (const int*)d_in[2];
  const float* Wg     = (const float*)d_in[3];
  const float* bg     = (const float*)d_in[4];
  const float* W1     = (const float*)d_in[5];
  const float* b1     = (const float*)d_in[6];
  const float* W2     = (const float*)d_in[7];
  const float* b2     = (const float*)d_in[8];
  float* out = (float*)d_out;

  short* xb       = (short*)d_ws;                                   // 512 KB
  float* partials = (float*)((char*)d_ws + 512 * 1024);             // 256*786*2 f32
  float* mix      = partials + (size_t)NB * NTILES_V * 2;
  float* stats    = mix + NB * 2;
  float* alphas   = stats + NB * 2;
  float* h        = alphas + NB * NS;

  // x -> bf16, pre-swizzled for linear global_load_lds staging
  prep_x<<<128, 256, 0, stream>>>(x, xb);
  // h = tanh(x @ W1 + b1)
  gemm_mfma<true><<<16, 256, 0, stream>>>(xb, W1, b1, h, nullptr, ND, 16);
  // mix = softmax2(h @ W2 + b2)
  gate_mix<<<NB, 256, 0, stream>>>(h, W2, b2, mix);
  // alphas = softmax(scores)
  softmax_scores<<<NB, 256, 0, stream>>>(scores, alphas);
  // logits = x @ Wg + bg -> d_out, fused per-row partial max/sum
  gemm_mfma<false><<<NTILES_V, 256, 0, stream>>>(xb, Wg, bg, out, partials, NV, NTILES_V);
  // combine partials -> stats
  combine_stats<<<NB, 256, 0, stream>>>(partials, stats, NTILES_V);
  // out = softmax * mix0 (in place)
  finalize_gen<<<dim3((NV + 255) / 256, NB), 256, 0, stream>>>(out, stats, mix);
  // scatter copy distribution
  scatter_copy<<<NB, NS, 0, stream>>>(out, alphas, ctx, mix);
}

// Round 5
// 200.918 us; speedup vs baseline: 16.9180x; 1.0234x over previous
//
#include <hip/hip_runtime.h>
#include <hip/hip_bf16.h>
#include <math.h>

constexpr int NB = 256;    // batch
constexpr int NS = 512;    // source positions
constexpr int ND = 1024;   // hidden
constexpr int NV = 50257;  // vocab
constexpr int NTILES_V = (NV + 63) / 64;   // 786

typedef __attribute__((ext_vector_type(8))) short bf16x8;
typedef __attribute__((ext_vector_type(4))) float f32x4;

__device__ __forceinline__ short f2bf(float f) {
  unsigned u = __builtin_bit_cast(unsigned, f);
  u = (u + 0x7FFFu + ((u >> 16) & 1u)) >> 16;   // RNE
  return (short)u;
}

// swizzle: chunk position = slot ^ swz(row). Self-inverse; used on write+read.
__device__ __forceinline__ int swz(int r) { return (r & 7) ^ ((r >> 3) & 1); }

__device__ __forceinline__ const bf16x8* fragAddr(const short* base, int r, int slot) {
  return reinterpret_cast<const bf16x8*>(
      reinterpret_cast<const char*>(base) + r * 128 + ((slot ^ swz(r)) << 4));
}

__device__ __forceinline__ void async_copy16(const void* gsrc, void* ldsdst) {
  __builtin_amdgcn_global_load_lds(
      (const __attribute__((address_space(1))) unsigned int*)gsrc,
      (__attribute__((address_space(3))) unsigned int*)ldsdst, 16, 0, 0);
}

// ---------------------------------------------------------------------------
// prep_x: xb[m][kt][chunkpos] bf16, pre-swizzled so GEMM A-staging is a linear
// global_load_lds copy. One 16B chunk (8 k) per thread.
// ---------------------------------------------------------------------------
__global__ __launch_bounds__(256)
void prep_x(const float* __restrict__ x, short* __restrict__ xb) {
  int idx = blockIdx.x * 256 + threadIdx.x;      // 32768 chunks
  int m = idx >> 7, kt = (idx >> 3) & 15, slot = idx & 7;
  const float4* src = reinterpret_cast<const float4*>(x + m * ND + kt * 64 + slot * 8);
  float4 f0 = src[0], f1 = src[1];
  bf16x8 v = { f2bf(f0.x), f2bf(f0.y), f2bf(f0.z), f2bf(f0.w),
               f2bf(f1.x), f2bf(f1.y), f2bf(f1.z), f2bf(f1.w) };
  *reinterpret_cast<bf16x8*>(reinterpret_cast<char*>(xb) +
      m * 2048 + kt * 128 + ((slot ^ swz(m)) << 4)) = v;
}

// ---------------------------------------------------------------------------
// MFMA GEMM: C[256,N] = act(x @ W + bias). BM=256 (full M, W streamed once),
// BN=64, BK=64, 4 waves, single-buffered LDS.
// Barrier discipline (T4): counted vmcnt(16) at the pre-compute barrier so the
// 16 HBM B-prefetch loads for t+1 stay in flight across it; only the 8
// L2-resident A-DMAs are drained. Order pinned by "memory" asm fences.
// ---------------------------------------------------------------------------
__device__ __forceinline__ void loadB(const float* __restrict__ W, int ldN, bool okc,
                                      int n0, int w, int lane, int t, float v[16]) {
#pragma unroll
  for (int i = 0; i < 16; ++i)
    v[i] = okc ? W[(size_t)(t * 64 + w * 16 + i) * ldN + n0 + lane] : 0.f;
}

__device__ __forceinline__ void gloadA(const short* __restrict__ xb,
                                       int w, int lane, int t, short* AsN) {
#pragma unroll
  for (int j = 0; j < 8; ++j) {
    int chunk = (w * 8 + j) * 64 + lane;         // 0..2047
    int ml = chunk >> 3, p = chunk & 7;
    const char* src = reinterpret_cast<const char*>(xb) +
        (ml << 11) + (t << 7) + (p << 4);
    async_copy16(src, reinterpret_cast<char*>(AsN) + ((w * 8 + j) << 10));
  }
}

__device__ __forceinline__ void transB(const float v[16], short* BsN, int w, int lane) {
  bf16x8 lo = { f2bf(v[0]), f2bf(v[1]), f2bf(v[2]), f2bf(v[3]),
                f2bf(v[4]), f2bf(v[5]), f2bf(v[6]), f2bf(v[7]) };
  bf16x8 hi = { f2bf(v[8]), f2bf(v[9]), f2bf(v[10]), f2bf(v[11]),
                f2bf(v[12]), f2bf(v[13]), f2bf(v[14]), f2bf(v[15]) };
  char* row = reinterpret_cast<char*>(BsN) + lane * 128;
  *reinterpret_cast<bf16x8*>(row + (((w * 2 + 0) ^ swz(lane)) << 4)) = lo;
  *reinterpret_cast<bf16x8*>(row + (((w * 2 + 1) ^ swz(lane)) << 4)) = hi;
}

__device__ __forceinline__ void computeStep(const short* A, const short* B,
                                            int w, int g, int c16, f32x4 acc[4][4]) {
#pragma unroll
  for (int kk = 0; kk < 2; ++kk) {
    int slot = kk * 4 + g;
    bf16x8 b[4];
#pragma unroll
    for (int ni = 0; ni < 4; ++ni) b[ni] = *fragAddr(B, ni * 16 + c16, slot);
#pragma unroll
    for (int mi = 0; mi < 4; ++mi) {
      bf16x8 a = *fragAddr(A, w * 64 + mi * 16 + c16, slot);
#pragma unroll
      for (int ni = 0; ni < 4; ++ni)
        acc[mi][ni] = __builtin_amdgcn_mfma_f32_16x16x32_bf16(a, b[ni], acc[mi][ni], 0, 0, 0);
    }
  }
}

template<bool GATE>
__global__ __launch_bounds__(256, 3)
void gemm_mfma(const short* __restrict__ xb, const float* __restrict__ W,
               const float* __restrict__ bias, float* __restrict__ Cout,
               float* __restrict__ partials, int N, int ntiles) {
  __shared__ __align__(16) short As[256 * 64];   // 32 KB
  __shared__ __align__(16) short Bs[64 * 64];    // 8 KB
  const int tid = threadIdx.x;
  const int lane = tid & 63, w = tid >> 6;
  const int g = lane >> 4, c16 = lane & 15;
  const int n0 = blockIdx.x * 64;
  const bool okc = (n0 + lane) < N;

  f32x4 acc[4][4] = {};
  float vbA[16], vbN[16];

  loadB(W, N, okc, n0, w, lane, 0, vbA);

#pragma unroll 1
  for (int t = 0; t < 16; ++t) {
    // barrier 1: all waves done reading As/Bs from step t-1 (their LDS reads
    // were consumed by MFMAs already -> no waitcnt needed, just rendezvous).
    asm volatile("" ::: "memory");
    __builtin_amdgcn_s_barrier();
    asm volatile("" ::: "memory");

    gloadA(xb, w, lane, t, As);             // 8 DMA issues -> As (L2-resident)
    asm volatile("" ::: "memory");          // pin: DMAs issue BEFORE B loads
    int tn = (t < 15) ? t + 1 : 15;         // last iter: redundant load keeps count
    loadB(W, N, okc, n0, w, lane, tn, vbN); // 16 HBM loads for t+1, stay in flight
    transB(vbA, Bs, w, lane);               // waits vbA (vmcnt(24) by compiler)

    // barrier 2: drain the 8 DMAs + own ds_writes; let the 16 vbN loads fly.
    asm volatile("s_waitcnt vmcnt(16) lgkmcnt(0)" ::: "memory");
    __builtin_amdgcn_s_barrier();
    asm volatile("" ::: "memory");

    computeStep(As, Bs, w, g, c16, acc);
#pragma unroll
    for (int i = 0; i < 16; ++i) vbA[i] = vbN[i];
  }

  // epilogue: C/D layout col = lane&15, row = (lane>>4)*4 + reg
#pragma unroll
  for (int mi = 0; mi < 4; ++mi) {
#pragma unroll
    for (int r = 0; r < 4; ++r) {
      int row = w * 64 + mi * 16 + g * 4 + r;
      float vals[4];
      float pm = -3.0e38f;
#pragma unroll
      for (int ni = 0; ni < 4; ++ni) {
        int col = n0 + ni * 16 + c16;
        bool ok2 = col < N;
        float bv = ok2 ? bias[col] : 0.f;
        float v = acc[mi][ni][r] + bv;
        if (GATE) v = tanhf(v);
        vals[ni] = v;
        if (ok2) {
          Cout[(size_t)row * N + col] = v;
          pm = fmaxf(pm, v);
        }
      }
      if (!GATE) {
        float ps = 0.f;
#pragma unroll
        for (int ni = 0; ni < 4; ++ni) {
          int col = n0 + ni * 16 + c16;
          if (col < N) ps += expf(vals[ni] - pm);
        }
#pragma unroll
        for (int o = 1; o < 16; o <<= 1) {
          float m2 = __shfl_xor(pm, o, 64);
          float s2 = __shfl_xor(ps, o, 64);
          float mn = fmaxf(pm, m2);
          ps = ps * expf(pm - mn) + s2 * expf(m2 - mn);
          pm = mn;
        }
        if (c16 == 0) {
          partials[((size_t)row * ntiles + blockIdx.x) * 2 + 0] = pm;
          partials[((size_t)row * ntiles + blockIdx.x) * 2 + 1] = ps;
        }
      }
    }
  }
}

// ---------------------------------------------------------------------------
// combine per-row partial (max,sum) over ntiles -> stats
// ---------------------------------------------------------------------------
__global__ __launch_bounds__(256)
void combine_stats(const float* __restrict__ partials, float* __restrict__ stats,
                   int ntiles) {
  int row = blockIdx.x, tid = threadIdx.x;
  float m = -3.0e38f, s = 0.f;
  for (int j = tid; j < ntiles; j += 256) {
    float pm = partials[((size_t)row * ntiles + j) * 2 + 0];
    float ps = partials[((size_t)row * ntiles + j) * 2 + 1];
    float mn = fmaxf(m, pm);
    s = s * expf(m - mn) + ps * expf(pm - mn);
    m = mn;
  }
#pragma unroll
  for (int o = 1; o < 64; o <<= 1) {
    float m2 = __shfl_xor(m, o, 64);
    float s2 = __shfl_xor(s, o, 64);
    float mn = fmaxf(m, m2);
    s = s * expf(m - mn) + s2 * expf(m2 - mn);
    m = mn;
  }
  __shared__ float lm[4], ls[4];
  int wv = tid >> 6, ln = tid & 63;
  if (ln == 0) { lm[wv] = m; ls[wv] = s; }
  __syncthreads();
  if (tid == 0) {
    float M = lm[0], S = ls[0];
    for (int k = 1; k < 4; ++k) {
      float mn = fmaxf(M, lm[k]);
      S = S * expf(M - mn) + ls[k] * expf(lm[k] - mn);
      M = mn;
    }
    stats[row * 2 + 0] = M;
    stats[row * 2 + 1] = S;
  }
}

// ---------------------------------------------------------------------------
// mix = softmax2(h @ W2 + b2), one block per row
// ---------------------------------------------------------------------------
__global__ __launch_bounds__(256)
void gate_mix(const float* __restrict__ h, const float* __restrict__ W2,
              const float* __restrict__ b2, float* __restrict__ mix) {
  const int row = blockIdx.x;
  const int tid = threadIdx.x;
  float g0 = 0.f, g1 = 0.f;
  for (int j = tid; j < ND; j += 256) {
    float hv = h[row * ND + j];
    g0 += hv * W2[j * 2 + 0];
    g1 += hv * W2[j * 2 + 1];
  }
  for (int o = 32; o > 0; o >>= 1) {
    g0 += __shfl_down(g0, o, 64);
    g1 += __shfl_down(g1, o, 64);
  }
  __shared__ float l0[4], l1[4];
  int wid = tid >> 6, lane = tid & 63;
  if (lane == 0) { l0[wid] = g0; l1[wid] = g1; }
  __syncthreads();
  if (tid == 0) {
    float a = l0[0] + l0[1] + l0[2] + l0[3] + b2[0];
    float c = l1[0] + l1[1] + l1[2] + l1[3] + b2[1];
    float m = fmaxf(a, c);
    float e0 = expf(a - m), e1 = expf(c - m);
    float inv = 1.f / (e0 + e1);
    mix[row * 2 + 0] = e0 * inv;
    mix[row * 2 + 1] = e1 * inv;
  }
}

// ---------------------------------------------------------------------------
// alphas = softmax(scores) rowwise
// ---------------------------------------------------------------------------
__global__ __launch_bounds__(256)
void softmax_scores(const float* __restrict__ scores, float* __restrict__ alphas) {
  const int row = blockIdx.x;
  const int tid = threadIdx.x;
  float v0 = scores[row * NS + tid];
  float v1 = scores[row * NS + tid + 256];
  float m = fmaxf(v0, v1);
  for (int o = 32; o > 0; o >>= 1) m = fmaxf(m, __shfl_down(m, o, 64));
  __shared__ float lm[4], ls[4];
  int wid = tid >> 6, lane = tid & 63;
  if (lane == 0) lm[wid] = m;
  __syncthreads();
  float mAll = fmaxf(fmaxf(lm[0], lm[1]), fmaxf(lm[2], lm[3]));
  float e0 = expf(v0 - mAll), e1 = expf(v1 - mAll);
  float s = e0 + e1;
  for (int o = 32; o > 0; o >>= 1) s += __shfl_down(s, o, 64);
  if (lane == 0) ls[wid] = s;
  __syncthreads();
  float inv = 1.f / (ls[0] + ls[1] + ls[2] + ls[3]);
  alphas[row * NS + tid] = e0 * inv;
  alphas[row * NS + tid + 256] = e1 * inv;
}

// ---------------------------------------------------------------------------
// out = exp(logit - m)/s * mix0   (in-place on d_out)
// ---------------------------------------------------------------------------
__global__ __launch_bounds__(256)
void finalize_gen(float* __restrict__ out, const float* __restrict__ stats,
                  const float* __restrict__ mix) {
  const int row = blockIdx.y;
  const int col = blockIdx.x * 256 + threadIdx.x;
  if (col < NV) {
    float m = stats[row * 2 + 0], s = stats[row * 2 + 1];
    float gmul = mix[row * 2 + 0];
    float x = out[(size_t)row * NV + col];
    out[(size_t)row * NV + col] = expf(x - m) * (gmul / s);
  }
}

// ---------------------------------------------------------------------------
// out[row, ctx_ids[row,s]] += alphas[row,s] * mix1[row]
// ---------------------------------------------------------------------------
__global__ __launch_bounds__(512)
void scatter_copy(float* __restrict__ out, const float* __restrict__ alphas,
                  const int* __restrict__ ids, const float* __restrict__ mix) {
  const int row = blockIdx.x;
  const int t = threadIdx.x;
  float a = alphas[row * NS + t] * mix[row * 2 + 1];
  atomicAdd(&out[(size_t)row * NV + ids[row * NS + t]], a);
}

extern "C" void kernel_launch(void* const* d_in, const int* in_sizes, int n_in,
                              void* d_out, int out_size, void* d_ws, size_t ws_size,
                              hipStream_t stream) {
  const float* x      = (const float*)d_in[0];
  const float* scores = (const float*)d_in[1];
  const int*   ctx    = (const int*)d_in[2];
  const float* Wg     = (const float*)d_in[3];
  const float* bg     = (const float*)d_in[4];
  const float* W1     = (const float*)d_in[5];
  const float* b1     = (const float*)d_in[6];
  const float* W2     = (const float*)d_in[7];
  const float* b2     = (const float*)d_in[8];
  float* out = (float*)d_out;

  short* xb       = (short*)d_ws;                                   // 512 KB
  float* partials = (float*)((char*)d_ws + 512 * 1024);             // 256*786*2 f32
  float* mix      = partials + (size_t)NB * NTILES_V * 2;
  float* stats    = mix + NB * 2;
  float* alphas   = stats + NB * 2;
  float* h        = alphas + NB * NS;

  // x -> bf16, pre-swizzled for linear global_load_lds staging
  prep_x<<<128, 256, 0, stream>>>(x, xb);
  // h = tanh(x @ W1 + b1)
  gemm_mfma<true><<<16, 256, 0, stream>>>(xb, W1, b1, h, nullptr, ND, 16);
  // mix = softmax2(h @ W2 + b2)
  gate_mix<<<NB, 256, 0, stream>>>(h, W2, b2, mix);
  // alphas = softmax(scores)
  softmax_scores<<<NB, 256, 0, stream>>>(scores, alphas);
  // logits = x @ Wg + bg -> d_out, fused per-row partial max/sum
  gemm_mfma<false><<<NTILES_V, 256, 0, stream>>>(xb, Wg, bg, out, partials, NV, NTILES_V);
  // combine partials -> stats
  combine_stats<<<NB, 256, 0, stream>>>(partials, stats, NTILES_V);
  // out = softmax * mix0 (in place)
  finalize_gen<<<dim3((NV + 255) / 256, NB), 256, 0, stream>>>(out, stats, mix);
  // scatter copy distribution
  scatter_copy<<<NB, NS, 0, stream>>>(out, alphas, ctx, mix);
}